// Round 14
// baseline (335.610 us; speedup 1.0000x reference)
//
#include <hip/hip_runtime.h>

#define H     128
#define BGR   32      // num graphs
#define NCONF 5
#define ND    1280    // drug nodes
#define FD    78      // drug in-features
#define ED    5120    // drug edges
#define NP    12800   // protein nodes per conf
#define FP    1280    // protein in-features
#define EP    204800  // protein edges per conf
#define MAXD  64      // max in-degree slot capacity (= wave width)

#define PROT_GEMM1_BLKS 1000      // 64000/64  (stage1: 64-row tiles)
#define PROT_S23_BLKS  1000       // 64000/64  (stage23: 64-row tiles, 4 blocks/CU)
#define DRUG_GEMM1_BLKS 20        // 1280/64 (f32 path)
#define DRUG_S23_BLKS  20         // 1280/64
#define PLACE_BLKS 4020           // (5*204800+5120)/256
#define PROT_MP_BLKS 16000        // 64000/4
#define DRUG_MP_BLKS 320          // 1280/4

typedef unsigned short u16;
typedef unsigned int   u32;
typedef __attribute__((ext_vector_type(8))) short bf16x8;
typedef __attribute__((ext_vector_type(4))) unsigned int u32x4;
typedef __attribute__((ext_vector_type(4))) unsigned short u16x4;
typedef __attribute__((ext_vector_type(8))) unsigned short u16x8;
typedef __attribute__((ext_vector_type(4))) float f32x4;

__device__ __forceinline__ u16 f2bf(float x) {            // RNE round
  u32 u = __float_as_uint(x);
  u32 r = (u + 0x7FFFu + ((u >> 16) & 1u)) >> 16;
  return (u16)r;
}
__device__ __forceinline__ float bf2f(u16 h) {
  return __uint_as_float(((u32)h) << 16);
}

__device__ __forceinline__ void gload16(const void* gsrc, void* lds) {
  __builtin_amdgcn_global_load_lds(
      (const __attribute__((address_space(1))) unsigned int*)gsrc,
      (__attribute__((address_space(3))) unsigned int*)lds, 16, 0, 0);
}

// split 8 f32 -> hi/lo bf16x8 (truncation split: hi=top16, lo=trunc16(x-hi))
__device__ __forceinline__ void cvt8(float4 p, float4 q, bf16x8& hi, bf16x8& lo) {
  float f[8] = {p.x, p.y, p.z, p.w, q.x, q.y, q.z, q.w};
  u32x4 h, l;
  #pragma unroll
  for (int j = 0; j < 4; ++j) {
    u32 u0 = __float_as_uint(f[2 * j]);
    u32 u1 = __float_as_uint(f[2 * j + 1]);
    u32 h0 = u0 & 0xFFFF0000u;
    u32 h1 = u1 & 0xFFFF0000u;
    h[j] = (h0 >> 16) | h1;
    float l0 = f[2 * j]     - __uint_as_float(h0);
    float l1 = f[2 * j + 1] - __uint_as_float(h1);
    l[j] = (__float_as_uint(l0) >> 16) | (__float_as_uint(l1) & 0xFFFF0000u);
  }
  union { u32x4 u; bf16x8 b; } ch, cl;
  ch.u = h; cl.u = l;
  hi = ch.b; lo = cl.b;
}

// ---------------- fused W split + deg-counter zeroing ----------------
__device__ __forceinline__ void splitW_chunk(
    const float* __restrict__ W, u16* __restrict__ wsW, int K, int g)
{
  int step = g >> 10;
  int r = g & 1023;
  int col = r >> 3, q = r & 7;
  int u = q ^ (col & 7);
  int kc = (u & 3) * 8;
  bool lo = u >= 4;
  int k0 = step * 32 + kc;
  u16x8 o;
  #pragma unroll
  for (int j = 0; j < 8; ++j) {
    float x = W[(size_t)(k0 + j) * 128 + col];
    u16 h = f2bf(x);
    o[j] = lo ? f2bf(x - bf2f(h)) : h;
  }
  *(u16x8*)(wsW + (size_t)g * 8) = o;
}

__global__ __launch_bounds__(256) void splitW_all_k(
    const float* __restrict__ Wp0, const float* __restrict__ Wp1,
    const float* __restrict__ Wp2, const float* __restrict__ Wd1,
    const float* __restrict__ Wd2,
    u16* __restrict__ o0, u16* __restrict__ o1, u16* __restrict__ o2,
    u16* __restrict__ o3, u16* __restrict__ o4,
    int* __restrict__ deg_p, int* __restrict__ deg_d)
{
  int g = blockIdx.x * 256 + threadIdx.x;
  for (int i = g; i < NCONF * NP + ND; i += 224 * 256) {
    if (i < NCONF * NP) deg_p[i] = 0;
    else                deg_d[i - NCONF * NP] = 0;
  }
  if      (g < 40960) splitW_chunk(Wp0, o0, FP, g);
  else if (g < 45056) splitW_chunk(Wp1, o1, H, g - 40960);
  else if (g < 49152) splitW_chunk(Wp2, o2, H, g - 45056);
  else if (g < 53248) splitW_chunk(Wd1, o3, H, g - 49152);
  else if (g < 57344) splitW_chunk(Wd2, o4, H, g - 53248);
}

// ---------------- stage1 GEMM body: 64-row tiles, f32 A split (3-MFMA) ----------------
__device__ __forceinline__ void gemm_pipe64_body(
    char* smemRaw, const float* __restrict__ A, const u16* __restrict__ wsW,
    u16* __restrict__ Cout, int K, int blk)
{
  u16* Wlds = (u16*)smemRaw;       // 2 bufs x 16KB
  const int t = threadIdx.x;
  const int wid = t >> 6, lane = t & 63;
  const int lane15 = lane & 15, lq = lane >> 4;
  const int m0 = blk * 64;
  const int NT = K >> 5;           // 40 for FP: even

  const float* Ar = A + (size_t)(m0 + wid * 16 + lane15) * K + lq * 8;
  const u16* sbase = wsW + (size_t)(wid * 4) * 512 + (size_t)lane * 8;

  f32x4 acc[8];
  #pragma unroll
  for (int j = 0; j < 8; ++j) acc[j] = (f32x4){0.f, 0.f, 0.f, 0.f};

  #define STAGE_W(step, buf) do {                                   \
    const u16* s_ = sbase + (size_t)(step) * 8192;                  \
    u16* d_ = &Wlds[(buf) * 8192 + wid * 2048];                     \
    gload16(s_,        d_);                                         \
    gload16(s_ + 512,  d_ + 512);                                   \
    gload16(s_ + 1024, d_ + 1024);                                  \
    gload16(s_ + 1536, d_ + 1536);                                  \
  } while (0)

  STAGE_W(0, 0);
  asm volatile("" ::: "memory");
  float4 xa0 = *(const float4*)(Ar);
  float4 xa1 = *(const float4*)(Ar + 4);
  asm volatile("" ::: "memory");
  float4 ya0 = *(const float4*)(Ar + 32);
  float4 ya1 = *(const float4*)(Ar + 36);

  #define BODY64(T, RA0, RA1) do {                                            \
    if ((T) < NT - 1) asm volatile("s_waitcnt vmcnt(2)\ns_barrier" ::: "memory"); \
    else              asm volatile("s_waitcnt vmcnt(0)\ns_barrier"  ::: "memory"); \
    if ((T) + 1 < NT) { STAGE_W((T) + 1, ((T) + 1) & 1); }                    \
    asm volatile("" ::: "memory");                                            \
    bf16x8 ah, al;                                                            \
    cvt8(RA0, RA1, ah, al);                                                   \
    if ((T) + 2 < NT) {                                                       \
      const float* p_ = Ar + (size_t)((T) + 2) * 32;                          \
      RA0 = *(const float4*)(p_); RA1 = *(const float4*)(p_ + 4);             \
    }                                                                         \
    const char* base_ = (const char*)&Wlds[((T) & 1) * 8192];                 \
    _Pragma("unroll")                                                         \
    for (int cb = 0; cb < 8; ++cb) {                                          \
      int col_ = cb * 16 + lane15;                                            \
      const char* cbp_ = base_ + col_ * 128;                                  \
      int sw_ = (col_ & 7) << 4;                                              \
      bf16x8 bh_ = *(const bf16x8*)(cbp_ + ((lq << 4) ^ sw_));                \
      bf16x8 bl_ = *(const bf16x8*)(cbp_ + (((lq | 4) << 4) ^ sw_));          \
      acc[cb] = __builtin_amdgcn_mfma_f32_16x16x32_bf16(ah, bh_, acc[cb], 0, 0, 0); \
      acc[cb] = __builtin_amdgcn_mfma_f32_16x16x32_bf16(al, bh_, acc[cb], 0, 0, 0); \
      acc[cb] = __builtin_amdgcn_mfma_f32_16x16x32_bf16(ah, bl_, acc[cb], 0, 0, 0); \
    }                                                                         \
  } while (0)

  for (int tt = 0; tt < NT; tt += 2) {
    BODY64(tt,     xa0, xa1);
    BODY64(tt + 1, ya0, ya1);
  }
  #undef BODY64
  #undef STAGE_W

  #pragma unroll
  for (int j = 0; j < 4; ++j) {
    int row = m0 + wid * 16 + lq * 4 + j;
    u16* Crow = Cout + (size_t)row * 128 + lane15;
    #pragma unroll
    for (int cb = 0; cb < 8; ++cb)
      Crow[cb * 16] = f2bf(acc[cb][j]);
  }
}

// ---------------- stage23 GEMM body: bf16 A (exact), 64-row tiles ----------------
// 4 waves x (16 rows x 128 cols). Per body: 4 W-stage + 1 A-load -> vmcnt(1).
// 16 MFMA/body. Same per-element accumulation order as the 128-row version.
__device__ __forceinline__ void gemm_pipe64_bf16A_body(
    char* smemRaw, const u16* __restrict__ A, const u16* __restrict__ wsW,
    u16* __restrict__ Cout, int K, int blk)
{
  u16* Wlds = (u16*)smemRaw;       // 2 bufs x 16KB
  const int t = threadIdx.x;
  const int wid = t >> 6, lane = t & 63;
  const int lane15 = lane & 15, lq = lane >> 4;
  const int m0 = blk * 64;
  const int NT = K >> 5;           // 4 for H: even

  const u16* Ar = A + (size_t)(m0 + wid * 16 + lane15) * K + lq * 8;
  const u16* sbase = wsW + (size_t)(wid * 4) * 512 + (size_t)lane * 8;

  f32x4 acc[8];
  #pragma unroll
  for (int j = 0; j < 8; ++j) acc[j] = (f32x4){0.f, 0.f, 0.f, 0.f};

  #define STAGE_W(step, buf) do {                                   \
    const u16* s_ = sbase + (size_t)(step) * 8192;                  \
    u16* d_ = &Wlds[(buf) * 8192 + wid * 2048];                     \
    gload16(s_,        d_);                                         \
    gload16(s_ + 512,  d_ + 512);                                   \
    gload16(s_ + 1024, d_ + 1024);                                  \
    gload16(s_ + 1536, d_ + 1536);                                  \
  } while (0)

  // Pre-loop (fenced): S0 (4), A(0) (1), A(1) (1) -> 6 outstanding.
  STAGE_W(0, 0);
  asm volatile("" ::: "memory");
  u16x8 xa = *(const u16x8*)(Ar);
  asm volatile("" ::: "memory");
  u16x8 ya = *(const u16x8*)(Ar + 32);

  // At body T's wait: in-flight order ... A(T), S(T), A(T+1). Need S(T),A(T)
  // done -> leave only A(T+1): vmcnt(1).
  #define BODYB64(T, RA) do {                                                 \
    if ((T) < NT - 1) asm volatile("s_waitcnt vmcnt(1)\ns_barrier" ::: "memory"); \
    else              asm volatile("s_waitcnt vmcnt(0)\ns_barrier"  ::: "memory"); \
    if ((T) + 1 < NT) { STAGE_W((T) + 1, ((T) + 1) & 1); }                    \
    asm volatile("" ::: "memory");                                            \
    union { u16x8 u; bf16x8 b; } ca_;                                         \
    ca_.u = RA;                                                               \
    bf16x8 a0 = ca_.b;                                                        \
    if ((T) + 2 < NT) {                                                       \
      RA = *(const u16x8*)(Ar + (size_t)((T) + 2) * 32);                      \
    }                                                                         \
    const char* base_ = (const char*)&Wlds[((T) & 1) * 8192];                 \
    _Pragma("unroll")                                                         \
    for (int cb = 0; cb < 8; ++cb) {                                          \
      int col_ = cb * 16 + lane15;                                            \
      const char* cbp_ = base_ + col_ * 128;                                  \
      int sw_ = (col_ & 7) << 4;                                              \
      bf16x8 bh_ = *(const bf16x8*)(cbp_ + ((lq << 4) ^ sw_));                \
      bf16x8 bl_ = *(const bf16x8*)(cbp_ + (((lq | 4) << 4) ^ sw_));          \
      acc[cb] = __builtin_amdgcn_mfma_f32_16x16x32_bf16(a0, bh_, acc[cb], 0, 0, 0); \
      acc[cb] = __builtin_amdgcn_mfma_f32_16x16x32_bf16(a0, bl_, acc[cb], 0, 0, 0); \
    }                                                                         \
  } while (0)

  for (int tt = 0; tt < NT; tt += 2) {
    BODYB64(tt,     xa);
    BODYB64(tt + 1, ya);
  }
  #undef BODYB64
  #undef STAGE_W

  #pragma unroll
  for (int j = 0; j < 4; ++j) {
    int row = m0 + wid * 16 + lq * 4 + j;
    u16* Crow = Cout + (size_t)row * 128 + lane15;
    #pragma unroll
    for (int cb = 0; cb < 8; ++cb)
      Crow[cb * 16] = f2bf(acc[cb][j]);
  }
}

// ---------------- f32 GEMM body (K=78 drug layer 0), bf16 output ----------------
__device__ __forceinline__ void gemm_f32_body(
    char* smemRaw, const float* __restrict__ A, const float* __restrict__ W,
    u16* __restrict__ Cout, int K, int blk)
{
  float* As = (float*)smemRaw;                 // [16][64]
  float* Bs = (float*)(smemRaw + 16 * 64 * 4); // [16][128]
  const int t = threadIdx.x;
  const int m0 = blk * 64;
  const int colg = (t & 31) * 4;
  const int rowg = (t >> 5) * 8;
  const int rA = t >> 2;
  const int cA = (t & 3) * 4;
  const int rB = t >> 4;
  const int cB = (t & 15) * 4;

  float acc[8][4] = {};

  for (int k0 = 0; k0 < K; k0 += 16) {
    __syncthreads();
    #pragma unroll
    for (int j = 0; j < 4; ++j) {
      int kk = k0 + cA + j;
      As[(cA + j) * 64 + rA] = (kk < K) ? A[(size_t)(m0 + rA) * K + kk] : 0.0f;
    }
    {
      int kk = k0 + rB;
      if (kk < K) {
        *(float4*)&Bs[rB * 128 + cB]      = *(const float4*)(W + (size_t)kk * 128 + cB);
        *(float4*)&Bs[rB * 128 + cB + 64] = *(const float4*)(W + (size_t)kk * 128 + cB + 64);
      } else {
        *(float4*)&Bs[rB * 128 + cB]      = make_float4(0.f, 0.f, 0.f, 0.f);
        *(float4*)&Bs[rB * 128 + cB + 64] = make_float4(0.f, 0.f, 0.f, 0.f);
      }
    }
    __syncthreads();
    #pragma unroll
    for (int k = 0; k < 16; ++k) {
      float4 b  = *(const float4*)&Bs[k * 128 + colg];
      float4 a0 = *(const float4*)&As[k * 64 + rowg];
      float4 a1 = *(const float4*)&As[k * 64 + rowg + 4];
      const float av[8] = {a0.x, a0.y, a0.z, a0.w, a1.x, a1.y, a1.z, a1.w};
      #pragma unroll
      for (int i = 0; i < 8; ++i) {
        acc[i][0] += av[i] * b.x;
        acc[i][1] += av[i] * b.y;
        acc[i][2] += av[i] * b.z;
        acc[i][3] += av[i] * b.w;
      }
    }
  }
  #pragma unroll
  for (int i = 0; i < 8; ++i) {
    u16x4 o;
    o[0] = f2bf(acc[i][0]); o[1] = f2bf(acc[i][1]);
    o[2] = f2bf(acc[i][2]); o[3] = f2bf(acc[i][3]);
    *(u16x4*)(Cout + (size_t)(m0 + rowg + i) * 128 + colg) = o;
  }
}

// ---------------- fused stage 1 + edge placement ----------------
__global__ __launch_bounds__(256, 4) void stage1_place_k(
    const float* __restrict__ pA, const u16* __restrict__ pW, u16* __restrict__ pC,
    const float* __restrict__ dA, const float* __restrict__ dW, u16* __restrict__ dC,
    const int* __restrict__ prot_ei, const int* __restrict__ drug_ei,
    int* __restrict__ deg_p, u16* __restrict__ slot_p,
    int* __restrict__ deg_d, u16* __restrict__ slot_d)
{
  __shared__ __align__(16) char smem[2 * 16384];
  int b = blockIdx.x;
  if (b < PROT_GEMM1_BLKS) {
    gemm_pipe64_body(smem, pA, pW, pC, FP, b);
    return;
  }
  b -= PROT_GEMM1_BLKS;
  if (b < DRUG_GEMM1_BLKS) {
    gemm_f32_body(smem, dA, dW, dC, FD, b);
    return;
  }
  b -= DRUG_GEMM1_BLKS;
  int idx = b * 256 + threadIdx.x;
  if (idx < NCONF * EP) {
    int c = idx / EP, e = idx - c * EP;
    const int* eic = prot_ei + (size_t)c * 2 * EP;
    int s = eic[e], d = eic[EP + e];
    int node = c * NP + d;
    int pos = atomicAdd(&deg_p[node], 1);
    if (pos < MAXD) slot_p[(size_t)node * MAXD + pos] = (u16)s;
  } else {
    idx -= NCONF * EP;
    if (idx < ED) {
      int s = drug_ei[idx], d = drug_ei[ED + idx];
      int pos = atomicAdd(&deg_d[d], 1);
      if (pos < MAXD) slot_d[(size_t)d * MAXD + pos] = (u16)s;
    }
  }
}

// ---------------- fused stages 2/3: protein + drug bf16-A pipe GEMM (K=128, 64-row) ----
__global__ __launch_bounds__(256, 4) void stage23_gemm_k(
    const u16* __restrict__ pA, const u16* __restrict__ pW, u16* __restrict__ pC,
    const u16* __restrict__ dA, const u16* __restrict__ dW, u16* __restrict__ dC)
{
  __shared__ __align__(16) char smem[2 * 16384];
  if (blockIdx.x < PROT_S23_BLKS)
    gemm_pipe64_bf16A_body(smem, pA, pW, pC, H, blockIdx.x);
  else
    gemm_pipe64_bf16A_body(smem, dA, dW, dC, H, blockIdx.x - PROT_S23_BLKS);
}

// ---------------- message passing body (lane-preloaded slots, 8-wide batches) ----
// Accumulation order identical to prior version: even global index -> a0,
// odd -> a1, same sequence; only load issue-width changed.
__device__ __forceinline__ void mp_body(
    const u16* __restrict__ h, u16* __restrict__ xout,
    const int* __restrict__ deg, const u16* __restrict__ slots,
    const float* __restrict__ bias, int wid, int nPer)
{
  int lane = threadIdx.x & 63;
  int c = wid / nPer;
  const int* dg = deg + (size_t)c * nPer;
  int v = wid - c * nPer;
  const u32* hc = (const u32*)(h + (size_t)c * nPer * H);   // row = 64 dwords
  const u16* sl = slots + (size_t)wid * MAXD;
  int degv = dg[v];
  float dv = rsqrtf((float)degv + 1.0f);
  int n = degv < MAXD ? degv : MAXD;

  // lane-parallel preload: lane j holds slot j and its dinv
  int sj = (lane < n) ? (int)sl[lane] : 0;
  float dj = (lane < n) ? rsqrtf((float)dg[sj] + 1.0f) : 0.0f;

  u32 us = ((const u32*)h)[(size_t)wid * 64 + lane];
  float a0x = __uint_as_float(us << 16) * dv;
  float a0y = __uint_as_float(us & 0xFFFF0000u) * dv;
  float a1x = 0.f, a1y = 0.f;
  int i = 0;
  for (; i + 8 <= n; i += 8) {
    int   s_[8];
    float d_[8];
    u32   u_[8];
    #pragma unroll
    for (int j = 0; j < 8; ++j) { s_[j] = __shfl(sj, i + j); d_[j] = __shfl(dj, i + j); }
    #pragma unroll
    for (int j = 0; j < 8; ++j) u_[j] = hc[(size_t)s_[j] * 64 + lane];
    #pragma unroll
    for (int j = 0; j < 8; j += 2) {
      a0x += __uint_as_float(u_[j] << 16) * d_[j];
      a0y += __uint_as_float(u_[j] & 0xFFFF0000u) * d_[j];
      a1x += __uint_as_float(u_[j + 1] << 16) * d_[j + 1];
      a1y += __uint_as_float(u_[j + 1] & 0xFFFF0000u) * d_[j + 1];
    }
  }
  for (; i + 4 <= n; i += 4) {
    int s0 = __shfl(sj, i),     s1 = __shfl(sj, i + 1);
    int s2 = __shfl(sj, i + 2), s3 = __shfl(sj, i + 3);
    float d0 = __shfl(dj, i),     d1 = __shfl(dj, i + 1);
    float d2 = __shfl(dj, i + 2), d3 = __shfl(dj, i + 3);
    u32 u0 = hc[(size_t)s0 * 64 + lane];
    u32 u1 = hc[(size_t)s1 * 64 + lane];
    u32 u2 = hc[(size_t)s2 * 64 + lane];
    u32 u3 = hc[(size_t)s3 * 64 + lane];
    a0x += __uint_as_float(u0 << 16) * d0;
    a0y += __uint_as_float(u0 & 0xFFFF0000u) * d0;
    a1x += __uint_as_float(u1 << 16) * d1;
    a1y += __uint_as_float(u1 & 0xFFFF0000u) * d1;
    a0x += __uint_as_float(u2 << 16) * d2;
    a0y += __uint_as_float(u2 & 0xFFFF0000u) * d2;
    a1x += __uint_as_float(u3 << 16) * d3;
    a1y += __uint_as_float(u3 & 0xFFFF0000u) * d3;
  }
  for (; i < n; ++i) {
    int s0 = __shfl(sj, i);
    float d0 = __shfl(dj, i);
    u32 u0 = hc[(size_t)s0 * 64 + lane];
    a0x += __uint_as_float(u0 << 16) * d0;
    a0y += __uint_as_float(u0 & 0xFFFF0000u) * d0;
  }
  int col = lane * 2;
  float ox = fmaxf((a0x + a1x) * dv + bias[col],     0.0f);
  float oy = fmaxf((a0y + a1y) * dv + bias[col + 1], 0.0f);
  u32 ow = (u32)f2bf(ox) | ((u32)f2bf(oy) << 16);
  ((u32*)xout)[(size_t)wid * 64 + lane] = ow;
}

// ---------------- fused message passing (protein + drug), XCD-swizzled ----------------
__global__ __launch_bounds__(256) void mp_all_k(
    const u16* __restrict__ hp, u16* __restrict__ xp,
    const int* __restrict__ degp, const u16* __restrict__ slotp,
    const float* __restrict__ biasp,
    const u16* __restrict__ hd, u16* __restrict__ xd,
    const int* __restrict__ degd, const u16* __restrict__ slotd,
    const float* __restrict__ biasd)
{
  int bid = blockIdx.x;
  int cpx = gridDim.x >> 3;                    // 2040
  bid = (bid & 7) * cpx + (bid >> 3);          // bijective XCD swizzle
  int wv = threadIdx.x >> 6;
  if (bid < PROT_MP_BLKS) {
    mp_body(hp, xp, degp, slotp, biasp, bid * 4 + wv, NP);
  } else {
    mp_body(hd, xd, degd, slotd, biasd, (bid - PROT_MP_BLKS) * 4 + wv, ND);
  }
}

// ---------------- fused mean pool (bf16 input) ----------------
__device__ __forceinline__ void pool_body(
    const u16* __restrict__ x, float* __restrict__ out, int blk, int npg)
{
  __shared__ float part[4][128];
  const int col = threadIdx.x & 127;
  const int rp  = threadIdx.x >> 7;
  size_t row0 = (size_t)blk * npg;
  float acc = 0.0f;
  for (int i = rp; i < npg; i += 4)
    acc += bf2f(x[(row0 + i) * H + col]);
  part[rp][col] = acc;
  __syncthreads();
  if (rp == 0)
    out[(size_t)blk * H + col] =
        (part[0][col] + part[1][col] + part[2][col] + part[3][col]) / (float)npg;
}

__global__ __launch_bounds__(512) void pool_all_k(
    const u16* __restrict__ xd, float* __restrict__ outd,
    const u16* __restrict__ xp, float* __restrict__ outp)
{
  if (blockIdx.x < BGR) pool_body(xd, outd, blockIdx.x, ND / BGR);
  else                  pool_body(xp, outp, blockIdx.x - BGR, NP / BGR);
}

// ---------------- attention + MLP, one block per batch element ----------------
__global__ __launch_bounds__(128) void attn_mlp_k(
    const float* __restrict__ drug_emb, const float* __restrict__ conf_pool,
    const float* __restrict__ Wq, const float* __restrict__ bq,
    const float* __restrict__ Wk, const float* __restrict__ bk,
    const float* __restrict__ Wv, const float* __restrict__ bv,
    const float* __restrict__ W1, const float* __restrict__ b1,
    const float* __restrict__ W2, const float* __restrict__ b2,
    float* __restrict__ out)
{
  const int b = blockIdx.x;
  const int hcol = threadIdx.x;
  __shared__ float de[H], pc[H], vals_s[NCONF][H], red[H], sc[NCONF], peS[H];

  de[hcol] = drug_emb[(size_t)b * H + hcol];
  __syncthreads();

  float qv = bq[hcol];
  for (int k = 0; k < H; ++k) qv += de[k] * Wq[k * H + hcol];

  for (int c = 0; c < NCONF; ++c) {
    __syncthreads();
    pc[hcol] = conf_pool[((size_t)c * BGR + b) * H + hcol];
    __syncthreads();
    float kk = bk[hcol], vv = bv[hcol];
    for (int k = 0; k < H; ++k) {
      float p = pc[k];
      kk += p * Wk[k * H + hcol];
      vv += p * Wv[k * H + hcol];
    }
    vals_s[c][hcol] = vv;
    red[hcol] = qv * kk;
    __syncthreads();
    for (int s = 64; s > 0; s >>= 1) {
      if (hcol < s) red[hcol] += red[hcol + s];
      __syncthreads();
    }
    if (hcol == 0) sc[c] = red[0] * 0.08838834764831845f;
  }
  __syncthreads();

  float m = sc[0];
  for (int c = 1; c < NCONF; ++c) m = fmaxf(m, sc[c]);
  float ex[NCONF], sum = 0.0f;
  for (int c = 0; c < NCONF; ++c) { ex[c] = expf(sc[c] - m); sum += ex[c]; }
  float inv = 1.0f / sum;
  if (hcol < NCONF) out[BGR + b * NCONF + hcol] = ex[hcol] * inv;

  float pe = 0.0f;
  for (int c = 0; c < NCONF; ++c) pe += (ex[c] * inv) * vals_s[c][hcol];
  peS[hcol] = pe;
  __syncthreads();

  float hid = b1[hcol];
  for (int k = 0; k < H; ++k) hid += de[k]  * W1[k * H + hcol];
  for (int k = 0; k < H; ++k) hid += peS[k] * W1[(H + k) * H + hcol];
  hid = fmaxf(hid, 0.0f);

  red[hcol] = hid * W2[hcol];
  __syncthreads();
  for (int s = 64; s > 0; s >>= 1) {
    if (hcol < s) red[hcol] += red[hcol + s];
    __syncthreads();
  }
  if (hcol == 0) out[b] = red[0] + b2[0];
}

extern "C" void kernel_launch(void* const* d_in, const int* in_sizes, int n_in,
                              void* d_out, int out_size, void* d_ws, size_t ws_size,
                              hipStream_t stream)
{
  const float* drug_x  = (const float*)d_in[0];
  const float* prot_x  = (const float*)d_in[1];
  const float* Wd0 = (const float*)d_in[2];  const float* bd0 = (const float*)d_in[3];
  const float* Wd1 = (const float*)d_in[4];  const float* bd1 = (const float*)d_in[5];
  const float* Wd2 = (const float*)d_in[6];  const float* bd2 = (const float*)d_in[7];
  const float* Wp0 = (const float*)d_in[8];  const float* bp0 = (const float*)d_in[9];
  const float* Wp1 = (const float*)d_in[10]; const float* bp1 = (const float*)d_in[11];
  const float* Wp2 = (const float*)d_in[12]; const float* bp2 = (const float*)d_in[13];
  const float* Wq  = (const float*)d_in[14]; const float* bq  = (const float*)d_in[15];
  const float* Wk  = (const float*)d_in[16]; const float* bk  = (const float*)d_in[17];
  const float* Wv  = (const float*)d_in[18]; const float* bv  = (const float*)d_in[19];
  const float* W1  = (const float*)d_in[20]; const float* b1  = (const float*)d_in[21];
  const float* W2  = (const float*)d_in[22]; const float* b2  = (const float*)d_in[23];
  const int* drug_ei = (const int*)d_in[24];
  const int* prot_ei = (const int*)d_in[25];
  float* out = (float*)d_out;

  char* base = (char*)d_ws;
  size_t off = 0;
  auto alloc = [&](size_t bytes) -> char* {
    char* p = base + off;
    off = (off + bytes + 255) & ~(size_t)255;
    return p;
  };
  int*   deg_p   = (int*)  alloc((size_t)NCONF * NP * 4);
  int*   deg_d   = (int*)  alloc((size_t)ND * 4);
  u16*   slot_p  = (u16*)  alloc((size_t)NCONF * NP * MAXD * 2);  // 8.2 MB
  u16*   slot_d  = (u16*)  alloc((size_t)ND * MAXD * 2);
  u16*   bufHp   = (u16*)  alloc((size_t)NCONF * NP * H * 2);     // bf16 h
  u16*   bufXp   = (u16*)  alloc((size_t)NCONF * NP * H * 2);     // bf16 X
  u16*   bufHd   = (u16*)  alloc((size_t)ND * H * 2);
  u16*   bufXd   = (u16*)  alloc((size_t)ND * H * 2);
  float* drugemb = (float*)alloc((size_t)BGR * H * 4);
  float* confp   = (float*)alloc((size_t)NCONF * BGR * H * 4);
  u16* Wp0ws = (u16*)alloc((size_t)FP * 512);
  u16* Wp1ws = (u16*)alloc((size_t)H * 512);
  u16* Wp2ws = (u16*)alloc((size_t)H * 512);
  u16* Wd1ws = (u16*)alloc((size_t)H * 512);
  u16* Wd2ws = (u16*)alloc((size_t)H * 512);

  // 1. fused weight split + deg zeroing
  splitW_all_k<<<224, 256, 0, stream>>>(Wp0, Wp1, Wp2, Wd1, Wd2,
                                        Wp0ws, Wp1ws, Wp2ws, Wd1ws, Wd2ws,
                                        deg_p, deg_d);

  // 2. fused stage-1 GEMMs (64-row tiles) + edge placement
  stage1_place_k<<<PROT_GEMM1_BLKS + DRUG_GEMM1_BLKS + PLACE_BLKS, 256, 0, stream>>>(
      prot_x, Wp0ws, bufHp, drug_x, Wd0, bufHd,
      prot_ei, drug_ei, deg_p, slot_p, deg_d, slot_d);

  // 3-7. remaining GCN layers
  mp_all_k<<<PROT_MP_BLKS + DRUG_MP_BLKS, 256, 0, stream>>>(
      bufHp, bufXp, deg_p, slot_p, bp0,
      bufHd, bufXd, deg_d, slot_d, bd0);
  stage23_gemm_k<<<PROT_S23_BLKS + DRUG_S23_BLKS, 256, 0, stream>>>(
      bufXp, Wp1ws, bufHp, bufXd, Wd1ws, bufHd);
  mp_all_k<<<PROT_MP_BLKS + DRUG_MP_BLKS, 256, 0, stream>>>(
      bufHp, bufXp, deg_p, slot_p, bp1,
      bufHd, bufXd, deg_d, slot_d, bd1);
  stage23_gemm_k<<<PROT_S23_BLKS + DRUG_S23_BLKS, 256, 0, stream>>>(
      bufXp, Wp2ws, bufHp, bufXd, Wd2ws, bufHd);
  mp_all_k<<<PROT_MP_BLKS + DRUG_MP_BLKS, 256, 0, stream>>>(
      bufHp, bufXp, deg_p, slot_p, bp2,
      bufHd, bufXd, deg_d, slot_d, bd2);

  // 8. fused pooling
  pool_all_k<<<BGR + NCONF * BGR, 512, 0, stream>>>(bufXd, drugemb, bufXp, confp);

  // 9. attention + MLP
  attn_mlp_k<<<BGR, 128, 0, stream>>>(drugemb, confp, Wq, bq, Wk, bk, Wv, bv,
                                      W1, b1, W2, b2, out);
}